// Round 8
// baseline (154.429 us; speedup 1.0000x reference)
//
#include <hip/hip_runtime.h>
#include <math.h>

#define NROWS 8192
#define DDIM  64
#define JSPLIT 32
#define JSPAN  (NROWS / JSPLIT)   // 256
#define LOG2E  1.4426950408889634f
#define SKIP_THR (-28.0f)         // exp2(-28)*8192 = 3e-5 on a sum >= 1
#define NBLK (NROWS / 256 * JSPLIT)  // 1024 pairwise blocks

typedef __bf16 bf16x8 __attribute__((ext_vector_type(8)));
typedef float  f32x4  __attribute__((ext_vector_type(4)));

// ws layout (floats): [0,512) mse_part | [512,8704) sum_s | [8704,16896) hp2 |
//   [16896] done_counter (int) | ebf @ 16900 floats (bf16) | ebl after

// ---- k1: convert | MSE partials | hp2 diag-MFMA | zero sum_s + done ----
__global__ __launch_bounds__(256)
void prep_kernel(const float* __restrict__ yt, const float* __restrict__ yp,
                 const float* __restrict__ enc,
                 __bf16* __restrict__ ebf, __bf16* __restrict__ ebl,
                 float* __restrict__ hp2, float* __restrict__ mse_part,
                 float* __restrict__ sum_s, int* __restrict__ done) {
    int bid = blockIdx.x;
    int t   = threadIdx.x;
    if (bid < 256) {
        int off = bid * 2048 + t * 8;
        const float4* e4 = (const float4*)(enc + off);
        float4 x = e4[0], y = e4[1];
        bf16x8 v, w;
        v[0]=(__bf16)x.x; v[1]=(__bf16)x.y; v[2]=(__bf16)x.z; v[3]=(__bf16)x.w;
        v[4]=(__bf16)y.x; v[5]=(__bf16)y.y; v[6]=(__bf16)y.z; v[7]=(__bf16)y.w;
        w[0]=(__bf16)(x.x*LOG2E); w[1]=(__bf16)(x.y*LOG2E);
        w[2]=(__bf16)(x.z*LOG2E); w[3]=(__bf16)(x.w*LOG2E);
        w[4]=(__bf16)(y.x*LOG2E); w[5]=(__bf16)(y.y*LOG2E);
        w[6]=(__bf16)(y.z*LOG2E); w[7]=(__bf16)(y.w*LOG2E);
        *(bf16x8*)(ebf + off) = v;
        *(bf16x8*)(ebl + off) = w;
    } else if (bid < 768) {
        int idx = (bid - 256) * 256 + t;
        const float4* t4 = (const float4*)yt;
        const float4* p4 = (const float4*)yp;
        float4 a = t4[idx], b = p4[idx];
        float dx=b.x-a.x, dy=b.y-a.y, dz=b.z-a.z, dw=b.w-a.w;
        float s = dx*dx + dy*dy + dz*dz + dw*dw;
        #pragma unroll
        for (int off = 32; off > 0; off >>= 1) s += __shfl_down(s, off, 64);
        __shared__ float ls[4];
        int lane = t & 63, w = t >> 6;
        if (lane == 0) ls[w] = s;
        __syncthreads();
        if (t == 0) mse_part[bid - 256] = ls[0] + ls[1] + ls[2] + ls[3];
    } else if (bid < 896) {
        // hp2 from diagonal tile: plain(A) x scaled(B) MFMA, same math as pairwise
        int wv = t >> 6, ln = t & 63;
        int tile = (bid - 768) * 4 + wv;           // 0..511
        int lm = ln & 15, lk = ln >> 4;
        const float* r = enc + (tile * 16 + lm) * DDIM;
        bf16x8 f0, f1, g0, g1;
        {
            const float4* q = (const float4*)(r + lk * 8);
            float4 x = q[0], y = q[1];
            f0[0]=(__bf16)x.x; f0[1]=(__bf16)x.y; f0[2]=(__bf16)x.z; f0[3]=(__bf16)x.w;
            f0[4]=(__bf16)y.x; f0[5]=(__bf16)y.y; f0[6]=(__bf16)y.z; f0[7]=(__bf16)y.w;
            g0[0]=(__bf16)(x.x*LOG2E); g0[1]=(__bf16)(x.y*LOG2E);
            g0[2]=(__bf16)(x.z*LOG2E); g0[3]=(__bf16)(x.w*LOG2E);
            g0[4]=(__bf16)(y.x*LOG2E); g0[5]=(__bf16)(y.y*LOG2E);
            g0[6]=(__bf16)(y.z*LOG2E); g0[7]=(__bf16)(y.w*LOG2E);
        }
        {
            const float4* q = (const float4*)(r + 32 + lk * 8);
            float4 x = q[0], y = q[1];
            f1[0]=(__bf16)x.x; f1[1]=(__bf16)x.y; f1[2]=(__bf16)x.z; f1[3]=(__bf16)x.w;
            f1[4]=(__bf16)y.x; f1[5]=(__bf16)y.y; f1[6]=(__bf16)y.z; f1[7]=(__bf16)y.w;
            g1[0]=(__bf16)(x.x*LOG2E); g1[1]=(__bf16)(x.y*LOG2E);
            g1[2]=(__bf16)(x.z*LOG2E); g1[3]=(__bf16)(x.w*LOG2E);
            g1[4]=(__bf16)(y.x*LOG2E); g1[5]=(__bf16)(y.y*LOG2E);
            g1[6]=(__bf16)(y.z*LOG2E); g1[7]=(__bf16)(y.w*LOG2E);
        }
        f32x4 acc = {0.f, 0.f, 0.f, 0.f};
        acc = __builtin_amdgcn_mfma_f32_16x16x32_bf16(f0, g0, acc, 0, 0, 0);
        acc = __builtin_amdgcn_mfma_f32_16x16x32_bf16(f1, g1, acc, 0, 0, 0);
        #pragma unroll
        for (int reg = 0; reg < 4; ++reg) {
            int rc = lk * 4 + reg;
            if (lm == rc) hp2[tile * 16 + rc] = 0.5f * acc[reg];
        }
    } else {
        int off = (bid - 896) * 2048 + t * 8;
        float4 z = make_float4(0.f, 0.f, 0.f, 0.f);
        ((float4*)(sum_s + off))[0] = z;
        ((float4*)(sum_s + off))[1] = z;
        if (bid == 896 && t == 0) *done = 0;
    }
}

// ---- k2: pairwise MFMA + skip-vote; LAST block finalizes in-kernel ----
__global__ __launch_bounds__(256)
__attribute__((amdgpu_waves_per_eu(1, 4)))
void pairwise_kernel(const __bf16* __restrict__ ebf, const __bf16* __restrict__ ebl,
                     const float* __restrict__ hp2, float* __restrict__ sum_s,
                     const float* __restrict__ mse_part, int* __restrict__ done,
                     float* __restrict__ out) {
    int t  = threadIdx.x;
    int wv = t >> 6, ln = t & 63;
    int lm = ln & 15, lk = ln >> 4;
    int I0 = (blockIdx.x * 4 + wv) * 64;
    int j0 = blockIdx.y * JSPAN;

    bf16x8 a[4][2];
    float  hi2[16];
    #pragma unroll
    for (int mt = 0; mt < 4; ++mt) {
        const __bf16* rp = ebf + (I0 + mt * 16 + lm) * DDIM + lk * 8;
        a[mt][0] = *(const bf16x8*)(rp);
        a[mt][1] = *(const bf16x8*)(rp + 32);
        #pragma unroll
        for (int reg = 0; reg < 4; ++reg)
            hi2[mt * 4 + reg] = hp2[I0 + mt * 16 + lk * 4 + reg];
    }
    float eacc[16];
    #pragma unroll
    for (int i = 0; i < 16; ++i) eacc[i] = 0.f;

    const __bf16* rp0 = ebl + (j0 + lm) * DDIM + lk * 8;
    bf16x8 b0 = *(const bf16x8*)(rp0);
    bf16x8 b1 = *(const bf16x8*)(rp0 + 32);
    float  nhj = -hp2[j0 + lm];

    for (int js = 0; js < JSPAN; js += 16) {
        int jn = (js + 16 < JSPAN) ? (j0 + js + 16) : j0;
        const __bf16* rpn = ebl + (jn + lm) * DDIM + lk * 8;
        bf16x8 pb0 = *(const bf16x8*)(rpn);
        bf16x8 pb1 = *(const bf16x8*)(rpn + 32);
        float  pnhj = -hp2[jn + lm];

        #pragma unroll
        for (int mt = 0; mt < 4; ++mt) {
            f32x4 acc = {nhj - hi2[mt * 4 + 0], nhj - hi2[mt * 4 + 1],
                         nhj - hi2[mt * 4 + 2], nhj - hi2[mt * 4 + 3]};
            acc = __builtin_amdgcn_mfma_f32_16x16x32_bf16(a[mt][0], b0, acc, 0, 0, 0);
            acc = __builtin_amdgcn_mfma_f32_16x16x32_bf16(a[mt][1], b1, acc, 0, 0, 0);
            float m = fmaxf(fmaxf(acc[0], acc[1]), fmaxf(acc[2], acc[3]));
            if (__any(m > SKIP_THR)) {
                #pragma unroll
                for (int reg = 0; reg < 4; ++reg)
                    eacc[mt * 4 + reg] += __builtin_amdgcn_exp2f(acc[reg]);
            }
        }
        b0 = pb0; b1 = pb1; nhj = pnhj;
    }
    #pragma unroll
    for (int i = 0; i < 16; ++i) {
        float v = eacc[i];
        v += __shfl_xor(v, 1, 64);
        v += __shfl_xor(v, 2, 64);
        v += __shfl_xor(v, 4, 64);
        v += __shfl_xor(v, 8, 64);
        if (lm == 0) {
            int mt = i >> 2, reg = i & 3;
            atomicAdd(&sum_s[I0 + mt * 16 + lk * 4 + reg], v);
        }
    }

    // ---- last-block finalize (saves one dispatch + launch gap) ----
    __threadfence();                                   // release our atomics
    __shared__ int lastFlag;
    if (t == 0) {
        int prev = atomicAdd(done, 1);
        lastFlag = (prev == NBLK - 1);
    }
    __syncthreads();
    if (!lastFlag) return;
    __threadfence();                                   // acquire others' atomics

    float s = 0.0f;
    #pragma unroll
    for (int u = 0; u < 32; ++u) {
        // coherent RMW-load: safe against cross-XCD L2 staleness
        float v = atomicAdd(&sum_s[t * 32 + u], 0.0f);
        s += __logf(v);
    }
    float m = mse_part[t] + mse_part[t + 256];         // prev-kernel data: visible
    #pragma unroll
    for (int off = 32; off > 0; off >>= 1) {
        s += __shfl_down(s, off, 64);
        m += __shfl_down(m, off, 64);
    }
    __shared__ float rs[4], rm[4];
    int lane = t & 63, w = t >> 6;
    if (lane == 0) { rs[w] = s; rm[w] = m; }
    __syncthreads();
    if (t == 0) {
        float tot = rs[0] + rs[1] + rs[2] + rs[3];
        float mtot = rm[0] + rm[1] + rm[2] + rm[3];
        float kde = tot / (float)NROWS;
        float c   = logf((float)NROWS);
        float IXT = (c - kde) / logf(2.0f);
        float mse = mtot / (float)(NROWS * DDIM);
        out[0] = 1.0f * IXT + 500.0f * mse;
        out[1] = IXT;
        out[2] = mse;
    }
}

extern "C" void kernel_launch(void* const* d_in, const int* in_sizes, int n_in,
                              void* d_out, int out_size, void* d_ws, size_t ws_size,
                              hipStream_t stream) {
    const float* y_true  = (const float*)d_in[0];
    const float* y_pred  = (const float*)d_in[1];
    const float* encoded = (const float*)d_in[2];
    float* out = (float*)d_out;

    float*  wsf      = (float*)d_ws;
    float*  mse_part = wsf;                        // 512
    float*  sum_s    = wsf + 512;                  // 8192
    float*  hp2      = wsf + 512 + NROWS;          // 8192
    int*    done     = (int*)(wsf + 512 + 2 * NROWS);
    __bf16* ebf      = (__bf16*)(wsf + 512 + 2 * NROWS + 4);  // 16B-aligned
    __bf16* ebl      = ebf + NROWS * DDIM;

    prep_kernel<<<900, 256, 0, stream>>>(y_true, y_pred, encoded,
                                         ebf, ebl, hp2, mse_part, sum_s, done);
    pairwise_kernel<<<dim3(NROWS / 256, JSPLIT), 256, 0, stream>>>(
        ebf, ebl, hp2, sum_s, mse_part, done, out);
}

// Round 9
// 108.169 us; speedup vs baseline: 1.4277x; 1.4277x over previous
//
#include <hip/hip_runtime.h>
#include <math.h>

#define NROWS 8192
#define DDIM  64
#define JSPLIT 32
#define JSPAN  (NROWS / JSPLIT)   // 256
#define LOG2E  1.4426950408889634f
#define SKIP_THR (-28.0f)         // exp2(-28)*8192 = 3e-5 on a sum >= 1
#define NBLK (NROWS / 256 * JSPLIT)  // 1024 pairwise blocks

typedef __bf16 bf16x8 __attribute__((ext_vector_type(8)));
typedef float  f32x4  __attribute__((ext_vector_type(4)));

// ws layout (floats): [0,512) mse_part | [512,8704) sum_s | [8704,16896) hp2 |
//   [16896] done_counter (int) | ebf @ 16900 floats (bf16) | ebl after

// ---- k1: convert | MSE partials | hp2 diag-MFMA | zero sum_s + done ----
__global__ __launch_bounds__(256)
void prep_kernel(const float* __restrict__ yt, const float* __restrict__ yp,
                 const float* __restrict__ enc,
                 __bf16* __restrict__ ebf, __bf16* __restrict__ ebl,
                 float* __restrict__ hp2, float* __restrict__ mse_part,
                 float* __restrict__ sum_s, int* __restrict__ done) {
    int bid = blockIdx.x;
    int t   = threadIdx.x;
    if (bid < 256) {
        int off = bid * 2048 + t * 8;
        const float4* e4 = (const float4*)(enc + off);
        float4 x = e4[0], y = e4[1];
        bf16x8 v, w;
        v[0]=(__bf16)x.x; v[1]=(__bf16)x.y; v[2]=(__bf16)x.z; v[3]=(__bf16)x.w;
        v[4]=(__bf16)y.x; v[5]=(__bf16)y.y; v[6]=(__bf16)y.z; v[7]=(__bf16)y.w;
        w[0]=(__bf16)(x.x*LOG2E); w[1]=(__bf16)(x.y*LOG2E);
        w[2]=(__bf16)(x.z*LOG2E); w[3]=(__bf16)(x.w*LOG2E);
        w[4]=(__bf16)(y.x*LOG2E); w[5]=(__bf16)(y.y*LOG2E);
        w[6]=(__bf16)(y.z*LOG2E); w[7]=(__bf16)(y.w*LOG2E);
        *(bf16x8*)(ebf + off) = v;
        *(bf16x8*)(ebl + off) = w;
    } else if (bid < 768) {
        int idx = (bid - 256) * 256 + t;
        const float4* t4 = (const float4*)yt;
        const float4* p4 = (const float4*)yp;
        float4 a = t4[idx], b = p4[idx];
        float dx=b.x-a.x, dy=b.y-a.y, dz=b.z-a.z, dw=b.w-a.w;
        float s = dx*dx + dy*dy + dz*dz + dw*dw;
        #pragma unroll
        for (int off = 32; off > 0; off >>= 1) s += __shfl_down(s, off, 64);
        __shared__ float ls[4];
        int lane = t & 63, w = t >> 6;
        if (lane == 0) ls[w] = s;
        __syncthreads();
        if (t == 0) mse_part[bid - 256] = ls[0] + ls[1] + ls[2] + ls[3];
    } else if (bid < 896) {
        // hp2 from diagonal tile: plain(A) x scaled(B) MFMA, same math as pairwise
        int wv = t >> 6, ln = t & 63;
        int tile = (bid - 768) * 4 + wv;           // 0..511
        int lm = ln & 15, lk = ln >> 4;
        const float* r = enc + (tile * 16 + lm) * DDIM;
        bf16x8 f0, f1, g0, g1;
        {
            const float4* q = (const float4*)(r + lk * 8);
            float4 x = q[0], y = q[1];
            f0[0]=(__bf16)x.x; f0[1]=(__bf16)x.y; f0[2]=(__bf16)x.z; f0[3]=(__bf16)x.w;
            f0[4]=(__bf16)y.x; f0[5]=(__bf16)y.y; f0[6]=(__bf16)y.z; f0[7]=(__bf16)y.w;
            g0[0]=(__bf16)(x.x*LOG2E); g0[1]=(__bf16)(x.y*LOG2E);
            g0[2]=(__bf16)(x.z*LOG2E); g0[3]=(__bf16)(x.w*LOG2E);
            g0[4]=(__bf16)(y.x*LOG2E); g0[5]=(__bf16)(y.y*LOG2E);
            g0[6]=(__bf16)(y.z*LOG2E); g0[7]=(__bf16)(y.w*LOG2E);
        }
        {
            const float4* q = (const float4*)(r + 32 + lk * 8);
            float4 x = q[0], y = q[1];
            f1[0]=(__bf16)x.x; f1[1]=(__bf16)x.y; f1[2]=(__bf16)x.z; f1[3]=(__bf16)x.w;
            f1[4]=(__bf16)y.x; f1[5]=(__bf16)y.y; f1[6]=(__bf16)y.z; f1[7]=(__bf16)y.w;
            g1[0]=(__bf16)(x.x*LOG2E); g1[1]=(__bf16)(x.y*LOG2E);
            g1[2]=(__bf16)(x.z*LOG2E); g1[3]=(__bf16)(x.w*LOG2E);
            g1[4]=(__bf16)(y.x*LOG2E); g1[5]=(__bf16)(y.y*LOG2E);
            g1[6]=(__bf16)(y.z*LOG2E); g1[7]=(__bf16)(y.w*LOG2E);
        }
        f32x4 acc = {0.f, 0.f, 0.f, 0.f};
        acc = __builtin_amdgcn_mfma_f32_16x16x32_bf16(f0, g0, acc, 0, 0, 0);
        acc = __builtin_amdgcn_mfma_f32_16x16x32_bf16(f1, g1, acc, 0, 0, 0);
        #pragma unroll
        for (int reg = 0; reg < 4; ++reg) {
            int rc = lk * 4 + reg;
            if (lm == rc) hp2[tile * 16 + rc] = 0.5f * acc[reg];
        }
    } else {
        int off = (bid - 896) * 2048 + t * 8;
        float4 z = make_float4(0.f, 0.f, 0.f, 0.f);
        ((float4*)(sum_s + off))[0] = z;
        ((float4*)(sum_s + off))[1] = z;
        if (bid == 896 && t == 0) *done = 0;
    }
}

// ---- finalize tail, isolated from the main loop's register allocation ----
__device__ __attribute__((noinline))
void finalize_tail(float* __restrict__ sum_s, const float* __restrict__ mse_part,
                   float* __restrict__ out, int t) {
    float s = 0.0f;
    #pragma unroll
    for (int u = 0; u < 32; ++u) {
        // coherent RMW-load: executes at the coherence point, no fence needed
        float v = atomicAdd(&sum_s[t * 32 + u], 0.0f);
        s += __logf(v);
    }
    float m = mse_part[t] + mse_part[t + 256];         // prev-kernel data: visible
    #pragma unroll
    for (int off = 32; off > 0; off >>= 1) {
        s += __shfl_down(s, off, 64);
        m += __shfl_down(m, off, 64);
    }
    __shared__ float rs[4], rm[4];
    int lane = t & 63, w = t >> 6;
    if (lane == 0) { rs[w] = s; rm[w] = m; }
    __syncthreads();
    if (t == 0) {
        float tot  = rs[0] + rs[1] + rs[2] + rs[3];
        float mtot = rm[0] + rm[1] + rm[2] + rm[3];
        float kde = tot / (float)NROWS;
        float c   = logf((float)NROWS);
        float IXT = (c - kde) / logf(2.0f);
        float mse = mtot / (float)(NROWS * DDIM);
        out[0] = 1.0f * IXT + 500.0f * mse;
        out[1] = IXT;
        out[2] = mse;
    }
}

// ---- k2: pairwise MFMA + skip-vote; LAST block finalizes in-kernel ----
__global__ __launch_bounds__(256)
__attribute__((amdgpu_waves_per_eu(1, 4)))
void pairwise_kernel(const __bf16* __restrict__ ebf, const __bf16* __restrict__ ebl,
                     const float* __restrict__ hp2, float* __restrict__ sum_s,
                     const float* __restrict__ mse_part, int* __restrict__ done,
                     float* __restrict__ out) {
    int t  = threadIdx.x;
    int wv = t >> 6, ln = t & 63;
    int lm = ln & 15, lk = ln >> 4;
    int I0 = (blockIdx.x * 4 + wv) * 64;
    int j0 = blockIdx.y * JSPAN;

    bf16x8 a[4][2];
    float  hi2[16];
    #pragma unroll
    for (int mt = 0; mt < 4; ++mt) {
        const __bf16* rp = ebf + (I0 + mt * 16 + lm) * DDIM + lk * 8;
        a[mt][0] = *(const bf16x8*)(rp);
        a[mt][1] = *(const bf16x8*)(rp + 32);
        #pragma unroll
        for (int reg = 0; reg < 4; ++reg)
            hi2[mt * 4 + reg] = hp2[I0 + mt * 16 + lk * 4 + reg];
    }
    float eacc[16];
    #pragma unroll
    for (int i = 0; i < 16; ++i) eacc[i] = 0.f;

    const __bf16* rp0 = ebl + (j0 + lm) * DDIM + lk * 8;
    bf16x8 b0 = *(const bf16x8*)(rp0);
    bf16x8 b1 = *(const bf16x8*)(rp0 + 32);
    float  nhj = -hp2[j0 + lm];

    for (int js = 0; js < JSPAN; js += 16) {
        int jn = (js + 16 < JSPAN) ? (j0 + js + 16) : j0;
        const __bf16* rpn = ebl + (jn + lm) * DDIM + lk * 8;
        bf16x8 pb0 = *(const bf16x8*)(rpn);
        bf16x8 pb1 = *(const bf16x8*)(rpn + 32);
        float  pnhj = -hp2[jn + lm];

        #pragma unroll
        for (int mt = 0; mt < 4; ++mt) {
            f32x4 acc = {nhj - hi2[mt * 4 + 0], nhj - hi2[mt * 4 + 1],
                         nhj - hi2[mt * 4 + 2], nhj - hi2[mt * 4 + 3]};
            acc = __builtin_amdgcn_mfma_f32_16x16x32_bf16(a[mt][0], b0, acc, 0, 0, 0);
            acc = __builtin_amdgcn_mfma_f32_16x16x32_bf16(a[mt][1], b1, acc, 0, 0, 0);
            float m = fmaxf(fmaxf(acc[0], acc[1]), fmaxf(acc[2], acc[3]));
            if (__any(m > SKIP_THR)) {
                #pragma unroll
                for (int reg = 0; reg < 4; ++reg)
                    eacc[mt * 4 + reg] += __builtin_amdgcn_exp2f(acc[reg]);
            }
        }
        b0 = pb0; b1 = pb1; nhj = pnhj;
    }
    #pragma unroll
    for (int i = 0; i < 16; ++i) {
        float v = eacc[i];
        v += __shfl_xor(v, 1, 64);
        v += __shfl_xor(v, 2, 64);
        v += __shfl_xor(v, 4, 64);
        v += __shfl_xor(v, 8, 64);
        if (lm == 0) {
            int mt = i >> 2, reg = i & 3;
            atomicAdd(&sum_s[I0 + mt * 16 + lk * 4 + reg], v);
        }
    }

    // ---- last-block-done handoff. NO __threadfence (on 8-XCD gfx950 it
    // lowers to L2 writeback/invalidate: 1024 blocks x flush = ~60us stall,
    // round-8 lesson). Release = wait for our own device-scope atomics to
    // complete at the coherence point, then increment the counter.
    asm volatile("s_waitcnt vmcnt(0)" ::: "memory");
    __shared__ int lastFlag;
    if (t == 0) lastFlag = (atomicAdd(done, 1) == NBLK - 1);
    __syncthreads();
    if (!lastFlag) return;
    finalize_tail(sum_s, mse_part, out, t);
}

extern "C" void kernel_launch(void* const* d_in, const int* in_sizes, int n_in,
                              void* d_out, int out_size, void* d_ws, size_t ws_size,
                              hipStream_t stream) {
    const float* y_true  = (const float*)d_in[0];
    const float* y_pred  = (const float*)d_in[1];
    const float* encoded = (const float*)d_in[2];
    float* out = (float*)d_out;

    float*  wsf      = (float*)d_ws;
    float*  mse_part = wsf;                        // 512
    float*  sum_s    = wsf + 512;                  // 8192
    float*  hp2      = wsf + 512 + NROWS;          // 8192
    int*    done     = (int*)(wsf + 512 + 2 * NROWS);
    __bf16* ebf      = (__bf16*)(wsf + 512 + 2 * NROWS + 4);  // 16B-aligned
    __bf16* ebl      = ebf + NROWS * DDIM;

    prep_kernel<<<900, 256, 0, stream>>>(y_true, y_pred, encoded,
                                         ebf, ebl, hp2, mse_part, sum_s, done);
    pairwise_kernel<<<dim3(NROWS / 256, JSPLIT), 256, 0, stream>>>(
        ebf, ebl, hp2, sum_s, mse_part, done, out);
}

// Round 10
// 107.595 us; speedup vs baseline: 1.4353x; 1.0053x over previous
//
#include <hip/hip_runtime.h>
#include <math.h>

#define NROWS 8192
#define DDIM  64
#define JSPLIT 32
#define JSPAN  (NROWS / JSPLIT)   // 256
#define LOG2E  1.4426950408889634f
#define SKIP_THR (-28.0f)         // exp2(-28)*8192 = 3e-5 on a sum >= 1
#define NBLK (NROWS / 256 * JSPLIT)  // 1024 pairwise blocks

typedef __bf16 bf16x8 __attribute__((ext_vector_type(8)));
typedef float  f32x4  __attribute__((ext_vector_type(4)));

// Pin a value into registers: asm-defined values cannot be rematerialized
// from memory, so the compiler cannot sink the originating load into a loop.
// (Round 8/9 lesson: VGPR_Count=52 vs ~90 live => A-frags re-loaded from L2
// every j-iter => 50us latency-bound loop.)
#define PIN(x) asm volatile("" : "+v"(x))

// ws layout (floats): [0,512) mse_part | [512,8704) sum_s | [8704,16896) hp2 |
//   [16896] done_counter (int) | ebf @ 16900 floats (bf16) | ebl after

// ---- k1: convert | MSE partials | hp2 diag-MFMA | zero sum_s + done ----
__global__ __launch_bounds__(256)
void prep_kernel(const float* __restrict__ yt, const float* __restrict__ yp,
                 const float* __restrict__ enc,
                 __bf16* __restrict__ ebf, __bf16* __restrict__ ebl,
                 float* __restrict__ hp2, float* __restrict__ mse_part,
                 float* __restrict__ sum_s, int* __restrict__ done) {
    int bid = blockIdx.x;
    int t   = threadIdx.x;
    if (bid < 256) {
        int off = bid * 2048 + t * 8;
        const float4* e4 = (const float4*)(enc + off);
        float4 x = e4[0], y = e4[1];
        bf16x8 v, w;
        v[0]=(__bf16)x.x; v[1]=(__bf16)x.y; v[2]=(__bf16)x.z; v[3]=(__bf16)x.w;
        v[4]=(__bf16)y.x; v[5]=(__bf16)y.y; v[6]=(__bf16)y.z; v[7]=(__bf16)y.w;
        w[0]=(__bf16)(x.x*LOG2E); w[1]=(__bf16)(x.y*LOG2E);
        w[2]=(__bf16)(x.z*LOG2E); w[3]=(__bf16)(x.w*LOG2E);
        w[4]=(__bf16)(y.x*LOG2E); w[5]=(__bf16)(y.y*LOG2E);
        w[6]=(__bf16)(y.z*LOG2E); w[7]=(__bf16)(y.w*LOG2E);
        *(bf16x8*)(ebf + off) = v;
        *(bf16x8*)(ebl + off) = w;
    } else if (bid < 768) {
        int idx = (bid - 256) * 256 + t;
        const float4* t4 = (const float4*)yt;
        const float4* p4 = (const float4*)yp;
        float4 a = t4[idx], b = p4[idx];
        float dx=b.x-a.x, dy=b.y-a.y, dz=b.z-a.z, dw=b.w-a.w;
        float s = dx*dx + dy*dy + dz*dz + dw*dw;
        #pragma unroll
        for (int off = 32; off > 0; off >>= 1) s += __shfl_down(s, off, 64);
        __shared__ float ls[4];
        int lane = t & 63, w = t >> 6;
        if (lane == 0) ls[w] = s;
        __syncthreads();
        if (t == 0) mse_part[bid - 256] = ls[0] + ls[1] + ls[2] + ls[3];
    } else if (bid < 896) {
        // hp2 from diagonal tile: plain(A) x scaled(B) MFMA, same math as pairwise
        int wv = t >> 6, ln = t & 63;
        int tile = (bid - 768) * 4 + wv;           // 0..511
        int lm = ln & 15, lk = ln >> 4;
        const float* r = enc + (tile * 16 + lm) * DDIM;
        bf16x8 f0, f1, g0, g1;
        {
            const float4* q = (const float4*)(r + lk * 8);
            float4 x = q[0], y = q[1];
            f0[0]=(__bf16)x.x; f0[1]=(__bf16)x.y; f0[2]=(__bf16)x.z; f0[3]=(__bf16)x.w;
            f0[4]=(__bf16)y.x; f0[5]=(__bf16)y.y; f0[6]=(__bf16)y.z; f0[7]=(__bf16)y.w;
            g0[0]=(__bf16)(x.x*LOG2E); g0[1]=(__bf16)(x.y*LOG2E);
            g0[2]=(__bf16)(x.z*LOG2E); g0[3]=(__bf16)(x.w*LOG2E);
            g0[4]=(__bf16)(y.x*LOG2E); g0[5]=(__bf16)(y.y*LOG2E);
            g0[6]=(__bf16)(y.z*LOG2E); g0[7]=(__bf16)(y.w*LOG2E);
        }
        {
            const float4* q = (const float4*)(r + 32 + lk * 8);
            float4 x = q[0], y = q[1];
            f1[0]=(__bf16)x.x; f1[1]=(__bf16)x.y; f1[2]=(__bf16)x.z; f1[3]=(__bf16)x.w;
            f1[4]=(__bf16)y.x; f1[5]=(__bf16)y.y; f1[6]=(__bf16)y.z; f1[7]=(__bf16)y.w;
            g1[0]=(__bf16)(x.x*LOG2E); g1[1]=(__bf16)(x.y*LOG2E);
            g1[2]=(__bf16)(x.z*LOG2E); g1[3]=(__bf16)(x.w*LOG2E);
            g1[4]=(__bf16)(y.x*LOG2E); g1[5]=(__bf16)(y.y*LOG2E);
            g1[6]=(__bf16)(y.z*LOG2E); g1[7]=(__bf16)(y.w*LOG2E);
        }
        f32x4 acc = {0.f, 0.f, 0.f, 0.f};
        acc = __builtin_amdgcn_mfma_f32_16x16x32_bf16(f0, g0, acc, 0, 0, 0);
        acc = __builtin_amdgcn_mfma_f32_16x16x32_bf16(f1, g1, acc, 0, 0, 0);
        #pragma unroll
        for (int reg = 0; reg < 4; ++reg) {
            int rc = lk * 4 + reg;
            if (lm == rc) hp2[tile * 16 + rc] = 0.5f * acc[reg];
        }
    } else {
        int off = (bid - 896) * 2048 + t * 8;
        float4 z = make_float4(0.f, 0.f, 0.f, 0.f);
        ((float4*)(sum_s + off))[0] = z;
        ((float4*)(sum_s + off))[1] = z;
        if (bid == 896 && t == 0) *done = 0;
    }
}

// ---- finalize tail, isolated from the main loop's register allocation ----
__device__ __attribute__((noinline))
void finalize_tail(float* __restrict__ sum_s, const float* __restrict__ mse_part,
                   float* __restrict__ out, int t) {
    float s = 0.0f;
    #pragma unroll
    for (int u = 0; u < 32; ++u) {
        // coherent RMW-load: executes at the coherence point, no fence needed
        float v = atomicAdd(&sum_s[t * 32 + u], 0.0f);
        s += __logf(v);
    }
    float m = mse_part[t] + mse_part[t + 256];         // prev-kernel data: visible
    #pragma unroll
    for (int off = 32; off > 0; off >>= 1) {
        s += __shfl_down(s, off, 64);
        m += __shfl_down(m, off, 64);
    }
    __shared__ float rs[4], rm[4];
    int lane = t & 63, w = t >> 6;
    if (lane == 0) { rs[w] = s; rm[w] = m; }
    __syncthreads();
    if (t == 0) {
        float tot  = rs[0] + rs[1] + rs[2] + rs[3];
        float mtot = rm[0] + rm[1] + rm[2] + rm[3];
        float kde = tot / (float)NROWS;
        float c   = logf((float)NROWS);
        float IXT = (c - kde) / logf(2.0f);
        float mse = mtot / (float)(NROWS * DDIM);
        out[0] = 1.0f * IXT + 500.0f * mse;
        out[1] = IXT;
        out[2] = mse;
    }
}

// ---- k2: pairwise MFMA + skip-vote; LAST block finalizes in-kernel ----
__global__ __launch_bounds__(256)
__attribute__((amdgpu_waves_per_eu(1, 4)))
void pairwise_kernel(const __bf16* __restrict__ ebf, const __bf16* __restrict__ ebl,
                     const float* __restrict__ hp2, float* __restrict__ sum_s,
                     const float* __restrict__ mse_part, int* __restrict__ done,
                     float* __restrict__ out) {
    int t  = threadIdx.x;
    int wv = t >> 6, ln = t & 63;
    int lm = ln & 15, lk = ln >> 4;
    int I0 = (blockIdx.x * 4 + wv) * 64;
    int j0 = blockIdx.y * JSPAN;

    bf16x8 a[4][2];
    float  hi2[16];
    #pragma unroll
    for (int mt = 0; mt < 4; ++mt) {
        const __bf16* rp = ebf + (I0 + mt * 16 + lm) * DDIM + lk * 8;
        a[mt][0] = *(const bf16x8*)(rp);
        a[mt][1] = *(const bf16x8*)(rp + 32);
        #pragma unroll
        for (int reg = 0; reg < 4; ++reg)
            hi2[mt * 4 + reg] = hp2[I0 + mt * 16 + lk * 4 + reg];
    }
    // Pin loop-invariant state in registers (defeat load-sinking; see top).
    #pragma unroll
    for (int mt = 0; mt < 4; ++mt) { PIN(a[mt][0]); PIN(a[mt][1]); }
    #pragma unroll
    for (int i = 0; i < 16; ++i) PIN(hi2[i]);

    float eacc[16];
    #pragma unroll
    for (int i = 0; i < 16; ++i) eacc[i] = 0.f;

    const __bf16* rp0 = ebl + (j0 + lm) * DDIM + lk * 8;
    bf16x8 b0 = *(const bf16x8*)(rp0);
    bf16x8 b1 = *(const bf16x8*)(rp0 + 32);
    float  nhj = -hp2[j0 + lm];

    for (int js = 0; js < JSPAN; js += 16) {
        int jn = (js + 16 < JSPAN) ? (j0 + js + 16) : j0;
        const __bf16* rpn = ebl + (jn + lm) * DDIM + lk * 8;
        bf16x8 pb0 = *(const bf16x8*)(rpn);
        bf16x8 pb1 = *(const bf16x8*)(rpn + 32);
        float  pnhj = -hp2[jn + lm];

        #pragma unroll
        for (int mt = 0; mt < 4; ++mt) {
            f32x4 acc = {nhj - hi2[mt * 4 + 0], nhj - hi2[mt * 4 + 1],
                         nhj - hi2[mt * 4 + 2], nhj - hi2[mt * 4 + 3]};
            acc = __builtin_amdgcn_mfma_f32_16x16x32_bf16(a[mt][0], b0, acc, 0, 0, 0);
            acc = __builtin_amdgcn_mfma_f32_16x16x32_bf16(a[mt][1], b1, acc, 0, 0, 0);
            float m = fmaxf(fmaxf(acc[0], acc[1]), fmaxf(acc[2], acc[3]));
            if (__any(m > SKIP_THR)) {
                #pragma unroll
                for (int reg = 0; reg < 4; ++reg)
                    eacc[mt * 4 + reg] += __builtin_amdgcn_exp2f(acc[reg]);
            }
        }
        b0 = pb0; b1 = pb1; nhj = pnhj;
    }
    #pragma unroll
    for (int i = 0; i < 16; ++i) {
        float v = eacc[i];
        v += __shfl_xor(v, 1, 64);
        v += __shfl_xor(v, 2, 64);
        v += __shfl_xor(v, 4, 64);
        v += __shfl_xor(v, 8, 64);
        if (lm == 0) {
            int mt = i >> 2, reg = i & 3;
            atomicAdd(&sum_s[I0 + mt * 16 + lk * 4 + reg], v);
        }
    }

    // ---- last-block-done handoff (no __threadfence: round-8 L2-flush lesson).
    // Release = wait for our device-scope atomics to reach the coherence point.
    asm volatile("s_waitcnt vmcnt(0)" ::: "memory");
    __shared__ int lastFlag;
    if (t == 0) lastFlag = (atomicAdd(done, 1) == NBLK - 1);
    __syncthreads();
    if (!lastFlag) return;
    finalize_tail(sum_s, mse_part, out, t);
}

extern "C" void kernel_launch(void* const* d_in, const int* in_sizes, int n_in,
                              void* d_out, int out_size, void* d_ws, size_t ws_size,
                              hipStream_t stream) {
    const float* y_true  = (const float*)d_in[0];
    const float* y_pred  = (const float*)d_in[1];
    const float* encoded = (const float*)d_in[2];
    float* out = (float*)d_out;

    float*  wsf      = (float*)d_ws;
    float*  mse_part = wsf;                        // 512
    float*  sum_s    = wsf + 512;                  // 8192
    float*  hp2      = wsf + 512 + NROWS;          // 8192
    int*    done     = (int*)(wsf + 512 + 2 * NROWS);
    __bf16* ebf      = (__bf16*)(wsf + 512 + 2 * NROWS + 4);  // 16B-aligned
    __bf16* ebl      = ebf + NROWS * DDIM;

    prep_kernel<<<900, 256, 0, stream>>>(y_true, y_pred, encoded,
                                         ebf, ebl, hp2, mse_part, sum_s, done);
    pairwise_kernel<<<dim3(NROWS / 256, JSPLIT), 256, 0, stream>>>(
        ebf, ebl, hp2, sum_s, mse_part, done, out);
}

// Round 11
// 86.383 us; speedup vs baseline: 1.7877x; 1.2455x over previous
//
#include <hip/hip_runtime.h>
#include <math.h>

#define NROWS 8192
#define DDIM  64
#define JSPLIT 32
#define JSPAN  (NROWS / JSPLIT)   // 256
#define LOG2E  1.4426950408889634f
#define SKIP_THR (-28.0f)         // exp2(-28)*8192 = 3e-5 on a sum >= 1
#define APAD  72                  // LDS row stride in bf16: 144B -> bank-stride 4, 2-way (free)

typedef __bf16 bf16x8 __attribute__((ext_vector_type(8)));
typedef float  f32x4  __attribute__((ext_vector_type(4)));

// ws layout (floats): [0,512) mse_part | [512,8704) sum_s | [8704,16896) hp2 |
//   ebf @ 16896 floats (bf16) | ebl after

// ---- k1: convert | MSE partials | hp2 diag-MFMA | zero sum_s ----
__global__ __launch_bounds__(256)
void prep_kernel(const float* __restrict__ yt, const float* __restrict__ yp,
                 const float* __restrict__ enc,
                 __bf16* __restrict__ ebf, __bf16* __restrict__ ebl,
                 float* __restrict__ hp2, float* __restrict__ mse_part,
                 float* __restrict__ sum_s) {
    int bid = blockIdx.x;
    int t   = threadIdx.x;
    if (bid < 256) {
        int off = bid * 2048 + t * 8;
        const float4* e4 = (const float4*)(enc + off);
        float4 x = e4[0], y = e4[1];
        bf16x8 v, w;
        v[0]=(__bf16)x.x; v[1]=(__bf16)x.y; v[2]=(__bf16)x.z; v[3]=(__bf16)x.w;
        v[4]=(__bf16)y.x; v[5]=(__bf16)y.y; v[6]=(__bf16)y.z; v[7]=(__bf16)y.w;
        w[0]=(__bf16)(x.x*LOG2E); w[1]=(__bf16)(x.y*LOG2E);
        w[2]=(__bf16)(x.z*LOG2E); w[3]=(__bf16)(x.w*LOG2E);
        w[4]=(__bf16)(y.x*LOG2E); w[5]=(__bf16)(y.y*LOG2E);
        w[6]=(__bf16)(y.z*LOG2E); w[7]=(__bf16)(y.w*LOG2E);
        *(bf16x8*)(ebf + off) = v;
        *(bf16x8*)(ebl + off) = w;
    } else if (bid < 768) {
        int idx = (bid - 256) * 256 + t;
        const float4* t4 = (const float4*)yt;
        const float4* p4 = (const float4*)yp;
        float4 a = t4[idx], b = p4[idx];
        float dx=b.x-a.x, dy=b.y-a.y, dz=b.z-a.z, dw=b.w-a.w;
        float s = dx*dx + dy*dy + dz*dz + dw*dw;
        #pragma unroll
        for (int off = 32; off > 0; off >>= 1) s += __shfl_down(s, off, 64);
        __shared__ float ls[4];
        int lane = t & 63, w = t >> 6;
        if (lane == 0) ls[w] = s;
        __syncthreads();
        if (t == 0) mse_part[bid - 256] = ls[0] + ls[1] + ls[2] + ls[3];
    } else if (bid < 896) {
        // hp2 from diagonal tile: plain(A) x scaled(B) MFMA, same math as pairwise
        int wv = t >> 6, ln = t & 63;
        int tile = (bid - 768) * 4 + wv;           // 0..511
        int lm = ln & 15, lk = ln >> 4;
        const float* r = enc + (tile * 16 + lm) * DDIM;
        bf16x8 f0, f1, g0, g1;
        {
            const float4* q = (const float4*)(r + lk * 8);
            float4 x = q[0], y = q[1];
            f0[0]=(__bf16)x.x; f0[1]=(__bf16)x.y; f0[2]=(__bf16)x.z; f0[3]=(__bf16)x.w;
            f0[4]=(__bf16)y.x; f0[5]=(__bf16)y.y; f0[6]=(__bf16)y.z; f0[7]=(__bf16)y.w;
            g0[0]=(__bf16)(x.x*LOG2E); g0[1]=(__bf16)(x.y*LOG2E);
            g0[2]=(__bf16)(x.z*LOG2E); g0[3]=(__bf16)(x.w*LOG2E);
            g0[4]=(__bf16)(y.x*LOG2E); g0[5]=(__bf16)(y.y*LOG2E);
            g0[6]=(__bf16)(y.z*LOG2E); g0[7]=(__bf16)(y.w*LOG2E);
        }
        {
            const float4* q = (const float4*)(r + 32 + lk * 8);
            float4 x = q[0], y = q[1];
            f1[0]=(__bf16)x.x; f1[1]=(__bf16)x.y; f1[2]=(__bf16)x.z; f1[3]=(__bf16)x.w;
            f1[4]=(__bf16)y.x; f1[5]=(__bf16)y.y; f1[6]=(__bf16)y.z; f1[7]=(__bf16)y.w;
            g1[0]=(__bf16)(x.x*LOG2E); g1[1]=(__bf16)(x.y*LOG2E);
            g1[2]=(__bf16)(x.z*LOG2E); g1[3]=(__bf16)(x.w*LOG2E);
            g1[4]=(__bf16)(y.x*LOG2E); g1[5]=(__bf16)(y.y*LOG2E);
            g1[6]=(__bf16)(y.z*LOG2E); g1[7]=(__bf16)(y.w*LOG2E);
        }
        f32x4 acc = {0.f, 0.f, 0.f, 0.f};
        acc = __builtin_amdgcn_mfma_f32_16x16x32_bf16(f0, g0, acc, 0, 0, 0);
        acc = __builtin_amdgcn_mfma_f32_16x16x32_bf16(f1, g1, acc, 0, 0, 0);
        #pragma unroll
        for (int reg = 0; reg < 4; ++reg) {
            int rc = lk * 4 + reg;
            if (lm == rc) hp2[tile * 16 + rc] = 0.5f * acc[reg];
        }
    } else {
        int off = (bid - 896) * 2048 + t * 8;
        float4 z = make_float4(0.f, 0.f, 0.f, 0.f);
        ((float4*)(sum_s + off))[0] = z;
        ((float4*)(sum_s + off))[1] = z;
    }
}

// ---- k2: A-strip staged in LDS (regalloc-immune); MFMA + skip-vote ----
__global__ __launch_bounds__(256)
void pairwise_kernel(const __bf16* __restrict__ ebf, const __bf16* __restrict__ ebl,
                     const float* __restrict__ hp2, float* __restrict__ sum_s) {
    __shared__ __bf16 alds[256 * APAD];   // 36864 B, padded vs 128B-stride conflicts
    __shared__ float  hlds[256];          // 1024 B

    int t  = threadIdx.x;
    int wv = t >> 6, ln = t & 63;
    int lm = ln & 15, lk = ln >> 4;
    int I0B = blockIdx.x * 256;           // block's row strip
    int j0  = blockIdx.y * JSPAN;

    // stage 256 A-rows + h once per block (one row per thread)
    {
        const bf16x8* src = (const bf16x8*)(ebf + (I0B + t) * DDIM);
        bf16x8* dst = (bf16x8*)(alds + t * APAD);
        #pragma unroll
        for (int k = 0; k < 8; ++k) dst[k] = src[k];
        hlds[t] = hp2[I0B + t];
    }
    __syncthreads();

    float eacc[16];
    #pragma unroll
    for (int i = 0; i < 16; ++i) eacc[i] = 0.f;

    // B-side software pipeline (per-iter state only: no big live set)
    const __bf16* rp0 = ebl + (j0 + lm) * DDIM + lk * 8;
    bf16x8 b0 = *(const bf16x8*)(rp0);
    bf16x8 b1 = *(const bf16x8*)(rp0 + 32);
    float  nhj = -hp2[j0 + lm];

    for (int js = 0; js < JSPAN; js += 16) {
        int jn = (js + 16 < JSPAN) ? (j0 + js + 16) : j0;
        const __bf16* rpn = ebl + (jn + lm) * DDIM + lk * 8;
        bf16x8 pb0 = *(const bf16x8*)(rpn);
        bf16x8 pb1 = *(const bf16x8*)(rpn + 32);
        float  pnhj = -hp2[jn + lm];

        #pragma unroll
        for (int mt = 0; mt < 4; ++mt) {
            int arow = wv * 64 + mt * 16 + lm;
            const bf16x8* ap = (const bf16x8*)(alds + arow * APAD);
            bf16x8 a0 = ap[lk];           // elems lk*8      (ds_read_b128)
            bf16x8 a1 = ap[4 + lk];       // elems 32+lk*8   (ds_read_b128)
            const f32x4 hv = *(const f32x4*)(hlds + wv * 64 + mt * 16 + lk * 4);
            f32x4 acc = {nhj - hv[0], nhj - hv[1], nhj - hv[2], nhj - hv[3]};
            acc = __builtin_amdgcn_mfma_f32_16x16x32_bf16(a0, b0, acc, 0, 0, 0);
            acc = __builtin_amdgcn_mfma_f32_16x16x32_bf16(a1, b1, acc, 0, 0, 0);
            float m = fmaxf(fmaxf(acc[0], acc[1]), fmaxf(acc[2], acc[3]));
            if (__any(m > SKIP_THR)) {
                #pragma unroll
                for (int reg = 0; reg < 4; ++reg)
                    eacc[mt * 4 + reg] += __builtin_amdgcn_exp2f(acc[reg]);
            }
        }
        b0 = pb0; b1 = pb1; nhj = pnhj;
    }
    #pragma unroll
    for (int i = 0; i < 16; ++i) {
        float v = eacc[i];
        v += __shfl_xor(v, 1, 64);
        v += __shfl_xor(v, 2, 64);
        v += __shfl_xor(v, 4, 64);
        v += __shfl_xor(v, 8, 64);
        if (lm == 0) {
            int mt = i >> 2, reg = i & 3;
            atomicAdd(&sum_s[I0B + wv * 64 + mt * 16 + lk * 4 + reg], v);
        }
    }
}

// ---- k3: finalize (log-mean + mse partial sum + outputs) ----
__global__ __launch_bounds__(1024)
void finalize_kernel(const float* __restrict__ sum_s,
                     const float* __restrict__ mse_part,
                     float* __restrict__ out) {
    int t = threadIdx.x, lane = t & 63, w = t >> 6;
    float s = 0.0f;
    #pragma unroll
    for (int u = 0; u < 8; ++u) s += __logf(sum_s[t * 8 + u]);
    float m = (t < 512) ? mse_part[t] : 0.f;
    #pragma unroll
    for (int off = 32; off > 0; off >>= 1) {
        s += __shfl_down(s, off, 64);
        m += __shfl_down(m, off, 64);
    }
    __shared__ float rs[16], rm[16];
    if (lane == 0) { rs[w] = s; rm[w] = m; }
    __syncthreads();
    if (t == 0) {
        float tot = 0.f, mtot = 0.f;
        #pragma unroll
        for (int i = 0; i < 16; ++i) { tot += rs[i]; mtot += rm[i]; }
        float kde = tot / (float)NROWS;
        float c   = logf((float)NROWS);
        float IXT = (c - kde) / logf(2.0f);
        float mse = mtot / (float)(NROWS * DDIM);
        out[0] = 1.0f * IXT + 500.0f * mse;
        out[1] = IXT;
        out[2] = mse;
    }
}

extern "C" void kernel_launch(void* const* d_in, const int* in_sizes, int n_in,
                              void* d_out, int out_size, void* d_ws, size_t ws_size,
                              hipStream_t stream) {
    const float* y_true  = (const float*)d_in[0];
    const float* y_pred  = (const float*)d_in[1];
    const float* encoded = (const float*)d_in[2];
    float* out = (float*)d_out;

    float*  wsf      = (float*)d_ws;
    float*  mse_part = wsf;                        // 512
    float*  sum_s    = wsf + 512;                  // 8192
    float*  hp2      = wsf + 512 + NROWS;          // 8192
    __bf16* ebf      = (__bf16*)(wsf + 512 + 2 * NROWS);
    __bf16* ebl      = ebf + NROWS * DDIM;

    prep_kernel<<<900, 256, 0, stream>>>(y_true, y_pred, encoded,
                                         ebf, ebl, hp2, mse_part, sum_s);
    pairwise_kernel<<<dim3(NROWS / 256, JSPLIT), 256, 0, stream>>>(ebf, ebl, hp2, sum_s);
    finalize_kernel<<<1, 1024, 0, stream>>>(sum_s, mse_part, out);
}